// Round 3
// baseline (613.256 us; speedup 1.0000x reference)
//
#include <hip/hip_runtime.h>
#include <math.h>

#define B_ 16
#define S_ 1024
#define D_ 1024
#define NH_ 16
#define M_TOT (B_ * S_)

typedef __attribute__((ext_vector_type(8))) short short8v;
typedef __attribute__((ext_vector_type(4))) short short4v;
typedef __attribute__((ext_vector_type(4))) float float4v;
typedef __attribute__((ext_vector_type(4))) unsigned int uint4v;

static __device__ __forceinline__ unsigned short f2bf(float f) {
  union { float f; unsigned u; } x; x.f = f;
  unsigned r = (x.u + 0x7fffu + ((x.u >> 16) & 1u)) >> 16;
  return (unsigned short)r;
}
static __device__ __forceinline__ float bf2f(unsigned short u) {
  union { unsigned u; float f; } x; x.u = ((unsigned)u) << 16;
  return x.f;
}

// pack two f32 -> bf16x2 word, RNE (a -> low half).  Manual f2bf (known-RNE);
// v_cvt_pk_bf16_f32 failed accuracy in round 1 (rounding-mode mismatch).
static __device__ __forceinline__ unsigned pack2bf(float a, float b) {
  return ((unsigned)f2bf(b) << 16) | (unsigned)f2bf(a);
}

// async global->LDS, 16B per lane; LDS dest = wave-uniform base + lane*16 (m104)
static __device__ __forceinline__ void load_lds16(const unsigned short* g, unsigned short* l) {
  __builtin_amdgcn_global_load_lds(
      (const __attribute__((address_space(1))) unsigned int*)g,
      (__attribute__((address_space(3))) unsigned int*)l, 16, 0, 0);
}

// ---------------------------------------------------------------- RoPE tables
__global__ void build_tables(float* __restrict__ cos1, float* __restrict__ sin1,
                             float* __restrict__ cos2, float* __restrict__ sin2) {
  int t = blockIdx.x * 256 + threadIdx.x;
  if (t < S_ * 8) {
    int s = t >> 3, i = t & 7;
    double ang = (double)s * pow(10000.0, -(double)i / 8.0);
    cos1[t] = (float)cos(ang);
    sin1[t] = (float)sin(ang);
  } else if (t < S_ * 8 + 384) {
    int u = t - S_ * 8;
    int p = u / 12, j = u - p * 12;
    double ang = (double)p * pow(10000.0, -(double)j / 12.0);
    cos2[u] = (float)cos(ang);
    sin2[u] = (float)sin(ang);
  }
}

// ---------------------------------------------------------------- fp32 -> bf16
__global__ __launch_bounds__(256) void f32_to_bf16(
    const float* __restrict__ src, unsigned short* __restrict__ dst, int n4) {
  int i = blockIdx.x * 256 + threadIdx.x;
  if (i < n4) {
    float4 v = ((const float4*)src)[i];
    unsigned short t[4] = {f2bf(v.x), f2bf(v.y), f2bf(v.z), f2bf(v.w)};
    ((short4v*)dst)[i] = *(short4v*)t;
  }
}

// all four 1024x1024 weights in one launch (blockIdx.y selects the matrix)
__global__ __launch_bounds__(256) void w4_to_bf16(
    const float* __restrict__ w0, const float* __restrict__ w1,
    const float* __restrict__ w2, const float* __restrict__ w3,
    unsigned short* __restrict__ dst) {
  const float* srcs[4] = {w0, w1, w2, w3};
  const float* src = srcs[blockIdx.y];
  unsigned short* d = dst + (size_t)blockIdx.y * D_ * D_;
  int i = blockIdx.x * 256 + threadIdx.x;   // < D_*D_/4
  float4 v = ((const float4*)src)[i];
  unsigned short t[4] = {f2bf(v.x), f2bf(v.y), f2bf(v.z), f2bf(v.w)};
  ((short4v*)d)[i] = *(short4v*)t;
}

// ---------------------------------------------------------------- bf16 MFMA GEMM
// C[M,1024] = A[M,1024] @ W[1024,1024]^T + bias.  m97 structure: 128x128 tile,
// BK=32, global_load_lds dwordx4 staging, 8 ds_read_b128 + 16 MFMA /wave/K-step.
template <bool BF16OUT>
__global__ __launch_bounds__(256) void gemm_mfma(
    const unsigned short* __restrict__ A, const unsigned short* __restrict__ W,
    const float* __restrict__ bias, void* __restrict__ Cout) {
  __shared__ unsigned short As[128 * 32];   // [row][k] contiguous, no pad (m104)
  __shared__ unsigned short Bs[128 * 32];
  const int t = threadIdx.x;
  const int w = t >> 6, L = t & 63;
  const int c = L & 15, g = L >> 4;
  const int id = blockIdx.x;
  const int xcd = id & 7, slot = id >> 3;
  const int bn = (slot & 7) * 128;
  const int bm = ((slot >> 3) * 8 + xcd) * 128;

  const int srow = w * 32 + (L >> 2);
  const int sko = (L & 3) * 8;
  const unsigned short* gA = A + (size_t)(bm + srow) * D_ + sko;
  const unsigned short* gB = W + (size_t)(bn + srow) * D_ + sko;
  unsigned short* lA = As + w * 1024;
  unsigned short* lB = Bs + w * 1024;

  const int wm = (w >> 1) * 64, wn = (w & 1) * 64;

  float4v acc[4][4];
#pragma unroll
  for (int i = 0; i < 4; ++i)
#pragma unroll
    for (int j = 0; j < 4; ++j) acc[i][j] = (float4v){0.f, 0.f, 0.f, 0.f};

  for (int k0 = 0; k0 < D_; k0 += 32) {
    __syncthreads();
    load_lds16(gA + k0, lA);
    load_lds16(gA + k0 + 16 * D_, lA + 512);
    load_lds16(gB + k0, lB);
    load_lds16(gB + k0 + 16 * D_, lB + 512);
    __syncthreads();
    short8v af[4], bf[4];
#pragma unroll
    for (int i = 0; i < 4; ++i)
      af[i] = *(const short8v*)&As[(wm + 16 * i + c) * 32 + 8 * g];
#pragma unroll
    for (int j = 0; j < 4; ++j)
      bf[j] = *(const short8v*)&Bs[(wn + 16 * j + c) * 32 + 8 * g];
#pragma unroll
    for (int i = 0; i < 4; ++i)
#pragma unroll
      for (int j = 0; j < 4; ++j)
        acc[i][j] = __builtin_amdgcn_mfma_f32_16x16x32_bf16(af[i], bf[j], acc[i][j], 0, 0, 0);
  }
#pragma unroll
  for (int i = 0; i < 4; ++i)
#pragma unroll
    for (int r = 0; r < 4; ++r) {
      const size_t row = (size_t)bm + wm + 16 * i + 4 * g + r;
#pragma unroll
      for (int j = 0; j < 4; ++j) {
        const int col = bn + wn + 16 * j + c;
        float vv = acc[i][j][r] + bias[col];
        if (BF16OUT)
          ((unsigned short*)Cout)[row * D_ + col] = f2bf(vv);
        else
          ((float*)Cout)[row * D_ + col] = vv;
      }
    }
}

// ---------------------------------------------------------------- RoPE in place (bf16)
__global__ __launch_bounds__(256) void rope_inplace(
    unsigned short* q,
    const float* __restrict__ cos1, const float* __restrict__ sin1,
    const float* __restrict__ cos2, const float* __restrict__ sin2,
    float scale) {
  int tid = blockIdx.x * 256 + threadIdx.x;
  int u = tid & 511;
  int m = tid >> 9;
  int s = m & (S_ - 1);
  int head = u >> 5, w = u & 31;
  size_t base = (size_t)m * D_ + head * 64;
  size_t c0, c1;
  float cv, sv;
  if (w < 8) {
    c0 = base + 2 * w; c1 = c0 + 1;
    cv = cos1[s * 8 + w]; sv = sin1[s * 8 + w];
  } else if (w < 20) {
    int j = w - 8, x = s & 31;
    c0 = base + 16 + j; c1 = base + 28 + j;
    cv = cos2[x * 12 + j]; sv = sin2[x * 12 + j];
  } else {
    int j = w - 20, y = s >> 5;
    c0 = base + 40 + j; c1 = base + 52 + j;
    cv = cos2[y * 12 + j]; sv = sin2[y * 12 + j];
  }
  float a = bf2f(q[c0]), b = bf2f(q[c1]);
  q[c0] = f2bf((a * cv - b * sv) * scale);
  q[c1] = f2bf((a * sv + b * cv) * scale);
}

// ---------------------------------------------------------------- V transpose (bf16)
// vb [b][s][head*64+n]  ->  vT [b][head][n(64)][s(1024)]
__global__ __launch_bounds__(256) void v_transpose(
    const unsigned short* __restrict__ v, unsigned short* __restrict__ vT) {
  __shared__ unsigned short T[64][72];
  const int t = threadIdx.x;
  const int st0 = blockIdx.x * 64;
  const int hd = blockIdx.y, b = blockIdx.z;
  const unsigned short* src = v + ((size_t)b * S_ + st0) * D_ + hd * 64;
#pragma unroll
  for (int rep = 0; rep < 4; ++rep) {
    int id = t + rep * 256;
    int s = id >> 4, n4 = (id & 15) * 4;
    short4v val = *(const short4v*)(src + (size_t)s * D_ + n4);
    T[n4 + 0][s] = val[0]; T[n4 + 1][s] = val[1];
    T[n4 + 2][s] = val[2]; T[n4 + 3][s] = val[3];
  }
  __syncthreads();
  unsigned short* dst = vT + ((size_t)(b * NH_ + hd) * 64) * S_ + st0;
#pragma unroll
  for (int rep = 0; rep < 2; ++rep) {
    int id = t + rep * 256;
    int n = id >> 3, s8 = (id & 7) * 8;
    unsigned short tmp[8];
#pragma unroll
    for (int u2 = 0; u2 < 8; ++u2) tmp[u2] = T[n][s8 + u2];
    *(short8v*)(dst + (size_t)n * S_ + s8) = *(short8v*)tmp;
  }
}

// ---------------------------------------------------------------- MFMA flash attention
// grid = 2048 linear, swizzled: xcd=id%8, slot=id/8, qt=slot%8,
// pair=(slot/8)*8+xcd.  8 qt-blocks of a pair sit on ONE XCD -> K/V L2-resident.
//
// Round-3 structure: latency-bound diagnosis (23% occupancy, 60% no-issue
// cycles, dur invariant under inner-loop rewrite) -> cut peak register
// liveness to fit more waves.  Each kt-tile is split into two st-halves
// (k-cols 0-31 / 32-63): 8 QK MFMA -> softmax(16) -> bpermute -> 8 PV MFMA.
// Transients halve: sacc 32->16, vf 32->16, pk 16->8, ap 16->8 regs.
// kf[2st..2st+1] refilled for kt+1 right after the half-QK that kills them.
// s_setprio(1) around MFMA clusters (T5; waves are barrier-free/independent).
__global__ __launch_bounds__(256) void attn_mfma(
    const unsigned short* __restrict__ qb, const unsigned short* __restrict__ kb,
    const unsigned short* __restrict__ vT, unsigned short* __restrict__ out) {
  const int t = threadIdx.x;
  const int w = t >> 6;
  const int L = t & 63;
  const int c = L & 15;
  const int g = L >> 4;
  const int id = blockIdx.x;
  const int xcd = id & 7, slot = id >> 3;
  const int qt = slot & 7;
  const int pair = (slot >> 3) * 8 + xcd;
  const int b = pair >> 4, hd = pair & 15;
  const size_t mrow0 = (size_t)b * S_ + qt * 128 + w * 32;
  const int dcol0 = hd * 64;

  // bpermute pull addresses (byte = 4*src_lane)
  const int a_lo = (((L & 16) ? 32 : 0) + c) * 4;  // src g = 2*(g&1)
  const int a_hi = a_lo + 64;                      // src g = 2*(g&1)+1
  const bool ghi = (L >= 32);                      // g>=2 -> wants upper jl

  short8v aq[2][2];
#pragma unroll
  for (int i = 0; i < 2; ++i)
#pragma unroll
    for (int st = 0; st < 2; ++st)
      aq[i][st] = *(const short8v*)(qb + (mrow0 + 16 * i + c) * D_ + dcol0 + 32 * st + 8 * g);

  float4v oacc[2][4];
  float lsum[2] = {0.f, 0.f};
#pragma unroll
  for (int i = 0; i < 2; ++i)
#pragma unroll
    for (int jv = 0; jv < 4; ++jv) oacc[i][jv] = (float4v){0.f, 0.f, 0.f, 0.f};

  const unsigned short* vbase = vT + (size_t)(b * NH_ + hd) * 64 * S_;
  const unsigned short* kbb = kb + (size_t)b * S_ * D_ + dcol0;

  short8v kf[4][2];
#pragma unroll
  for (int j = 0; j < 4; ++j) {
    const unsigned short* kr = kbb + (size_t)(16 * j + c) * D_ + 8 * g;
    kf[j][0] = *(const short8v*)(kr);
    kf[j][1] = *(const short8v*)(kr + 32);
  }

#pragma unroll 1
  for (int kt = 0; kt < 16; ++kt) {
#pragma unroll
    for (int st = 0; st < 2; ++st) {
      // V fragments for this half (in flight across QK + softmax)
      short8v vfh[4];
#pragma unroll
      for (int jv = 0; jv < 4; ++jv)
        vfh[jv] = *(const short8v*)(vbase + (size_t)(16 * jv + c) * S_ + kt * 64 + 32 * st + 8 * g);
      // QK half: sacch[i][jl] = S^T for k-cols 16*(2st+jl)..+15
      float4v sacch[2][2];
#pragma unroll
      for (int i = 0; i < 2; ++i)
#pragma unroll
        for (int jl = 0; jl < 2; ++jl) sacch[i][jl] = (float4v){0.f, 0.f, 0.f, 0.f};
      __builtin_amdgcn_s_setprio(1);
#pragma unroll
      for (int jl = 0; jl < 2; ++jl)
#pragma unroll
        for (int i = 0; i < 2; ++i) {
          const int j = 2 * st + jl;
          sacch[i][jl] = __builtin_amdgcn_mfma_f32_16x16x32_bf16(kf[j][0], aq[i][0], sacch[i][jl], 0, 0, 0);
          sacch[i][jl] = __builtin_amdgcn_mfma_f32_16x16x32_bf16(kf[j][1], aq[i][1], sacch[i][jl], 0, 0, 0);
        }
      __builtin_amdgcn_s_setprio(0);
      // kf[2st..2st+1] now dead -> refill for tile kt+1
      if (kt < 15) {
#pragma unroll
        for (int jl = 0; jl < 2; ++jl) {
          const int j = 2 * st + jl;
          const unsigned short* kr = kbb + (size_t)((kt + 1) * 64 + 16 * j + c) * D_ + 8 * g;
          kf[j][0] = *(const short8v*)(kr);
          kf[j][1] = *(const short8v*)(kr + 32);
        }
      }
      // in-register softmax: exp + lane-local row-sum + pack pairs to bf16 (RNE)
      unsigned pkh[2][2][2];
#pragma unroll
      for (int i = 0; i < 2; ++i)
#pragma unroll
        for (int jl = 0; jl < 2; ++jl) {
          float p0 = __expf(sacch[i][jl][0]);
          float p1 = __expf(sacch[i][jl][1]);
          float p2 = __expf(sacch[i][jl][2]);
          float p3 = __expf(sacch[i][jl][3]);
          lsum[i] += (p0 + p1) + (p2 + p3);
          pkh[i][jl][0] = pack2bf(p0, p1);
          pkh[i][jl][1] = pack2bf(p2, p3);
        }
      // redistribute: aph[i] elem 8g+u = P[q=16i+c][k=32st+8g+u]
      short8v aph[2];
#pragma unroll
      for (int i = 0; i < 2; ++i) {
        uint4v wv;
#pragma unroll
        for (int q2 = 0; q2 < 4; ++q2) {
          const int addr = (q2 & 2) ? a_hi : a_lo;
          int vlo = __builtin_amdgcn_ds_bpermute(addr, (int)pkh[i][0][q2 & 1]);
          int vhi = __builtin_amdgcn_ds_bpermute(addr, (int)pkh[i][1][q2 & 1]);
          wv[q2] = (unsigned)(ghi ? vhi : vlo);
        }
        aph[i] = *(short8v*)&wv;
      }
      // PV half: accumulate this st's k-contribution
      __builtin_amdgcn_s_setprio(1);
#pragma unroll
      for (int jv = 0; jv < 4; ++jv)
#pragma unroll
        for (int i = 0; i < 2; ++i)
          oacc[i][jv] = __builtin_amdgcn_mfma_f32_16x16x32_bf16(aph[i], vfh[jv], oacc[i][jv], 0, 0, 0);
      __builtin_amdgcn_s_setprio(0);
    }
  }
#pragma unroll
  for (int i = 0; i < 2; ++i) {
    float ls = lsum[i];
    ls += __shfl_xor(ls, 16);
    ls += __shfl_xor(ls, 32);
#pragma unroll
    for (int r = 0; r < 4; ++r) {
      // output row q=16i+4g+r; its denominator lives at lane 4g+r
      float inv = 1.f / __shfl(ls, 4 * g + r);
      size_t row = mrow0 + 16 * i + 4 * g + r;
#pragma unroll
      for (int jv = 0; jv < 4; ++jv)
        out[row * D_ + dcol0 + 16 * jv + c] = f2bf(oacc[i][jv][r] * inv);
    }
  }
}

// ---------------------------------------------------------------- launch
// Workspace (peak 168.03 MB < 192 MB proven):
//   [0,32)MB xb (reused as ob after QKV gemms) | [32,64) qb | [64,96) kb
//   [96,128) vb | [128,160) vT | [160,168) wqb,wkb,wvb,wob | [168,+32KB) tables
extern "C" void kernel_launch(void* const* d_in, const int* in_sizes, int n_in,
                              void* d_out, int out_size, void* d_ws, size_t ws_size,
                              hipStream_t stream) {
  const float* x  = (const float*)d_in[0];
  const float* Wq = (const float*)d_in[1];
  const float* bq = (const float*)d_in[2];
  const float* Wk = (const float*)d_in[3];
  const float* bk = (const float*)d_in[4];
  const float* Wv = (const float*)d_in[5];
  const float* bv = (const float*)d_in[6];
  const float* Wo = (const float*)d_in[7];
  const float* bo = (const float*)d_in[8];
  float* out = (float*)d_out;

  char* ws = (char*)d_ws;
  const size_t SZ2 = (size_t)M_TOT * D_ * 2;   // 32 MB
  unsigned short* xb = (unsigned short*)(ws);
  unsigned short* ob = xb;                               // alias: free after QKV gemms
  unsigned short* qb = (unsigned short*)(ws + SZ2);
  unsigned short* kb = (unsigned short*)(ws + 2 * SZ2);
  unsigned short* vb = (unsigned short*)(ws + 3 * SZ2);
  unsigned short* vT = (unsigned short*)(ws + 4 * SZ2);
  unsigned short* wqb = (unsigned short*)(ws + 5 * SZ2);
  unsigned short* wkb = wqb + (size_t)D_ * D_;
  unsigned short* wvb = wkb + (size_t)D_ * D_;
  unsigned short* wob = wvb + (size_t)D_ * D_;
  float* cos1 = (float*)(ws + 5 * SZ2 + 4 * (size_t)D_ * D_ * 2);
  float* sin1 = cos1 + S_ * 8;
  float* cos2 = sin1 + S_ * 8;
  float* sin2 = cos2 + 384;

  build_tables<<<34, 256, 0, stream>>>(cos1, sin1, cos2, sin2);

  f32_to_bf16<<<M_TOT * D_ / 4 / 256, 256, 0, stream>>>(x, xb, M_TOT * D_ / 4);
  w4_to_bf16<<<dim3(D_ * D_ / 4 / 256, 4), 256, 0, stream>>>(Wq, Wk, Wv, Wo, wqb);

  gemm_mfma<true><<<1024, 256, 0, stream>>>(xb, wqb, bq, qb);
  gemm_mfma<true><<<1024, 256, 0, stream>>>(xb, wkb, bk, kb);
  gemm_mfma<true><<<1024, 256, 0, stream>>>(xb, wvb, bv, vb);

  const int rope_blocks = (M_TOT * 512) / 256;
  rope_inplace<<<rope_blocks, 256, 0, stream>>>(qb, cos1, sin1, cos2, sin2, 0.125f);
  rope_inplace<<<rope_blocks, 256, 0, stream>>>(kb, cos1, sin1, cos2, sin2, 1.0f);
  v_transpose<<<dim3(16, 16, 16), 256, 0, stream>>>(vb, vT);

  attn_mfma<<<2048, 256, 0, stream>>>(qb, kb, vT, ob);

  gemm_mfma<false><<<1024, 256, 0, stream>>>(ob, wob, bo, out);
}

// Round 4
// 491.443 us; speedup vs baseline: 1.2479x; 1.2479x over previous
//
#include <hip/hip_runtime.h>
#include <math.h>

#define B_ 16
#define S_ 1024
#define D_ 1024
#define NH_ 16
#define M_TOT (B_ * S_)

typedef __attribute__((ext_vector_type(8))) short short8v;
typedef __attribute__((ext_vector_type(4))) short short4v;
typedef __attribute__((ext_vector_type(4))) float float4v;
typedef __attribute__((ext_vector_type(4))) unsigned int uint4v;

static __device__ __forceinline__ unsigned short f2bf(float f) {
  union { float f; unsigned u; } x; x.f = f;
  unsigned r = (x.u + 0x7fffu + ((x.u >> 16) & 1u)) >> 16;
  return (unsigned short)r;
}
static __device__ __forceinline__ float bf2f(unsigned short u) {
  union { unsigned u; float f; } x; x.u = ((unsigned)u) << 16;
  return x.f;
}

// pack two f32 -> bf16x2 word, RNE (a -> low half).  Manual f2bf (known-RNE);
// v_cvt_pk_bf16_f32 failed accuracy in round 1 (rounding-mode mismatch).
static __device__ __forceinline__ unsigned pack2bf(float a, float b) {
  return ((unsigned)f2bf(b) << 16) | (unsigned)f2bf(a);
}

// async global->LDS, 16B per lane; LDS dest = wave-uniform base + lane*16 (m104)
static __device__ __forceinline__ void load_lds16(const unsigned short* g, unsigned short* l) {
  __builtin_amdgcn_global_load_lds(
      (const __attribute__((address_space(1))) unsigned int*)g,
      (__attribute__((address_space(3))) unsigned int*)l, 16, 0, 0);
}

// ---------------------------------------------------------------- RoPE tables
__global__ void build_tables(float* __restrict__ cos1, float* __restrict__ sin1,
                             float* __restrict__ cos2, float* __restrict__ sin2) {
  int t = blockIdx.x * 256 + threadIdx.x;
  if (t < S_ * 8) {
    int s = t >> 3, i = t & 7;
    double ang = (double)s * pow(10000.0, -(double)i / 8.0);
    cos1[t] = (float)cos(ang);
    sin1[t] = (float)sin(ang);
  } else if (t < S_ * 8 + 384) {
    int u = t - S_ * 8;
    int p = u / 12, j = u - p * 12;
    double ang = (double)p * pow(10000.0, -(double)j / 12.0);
    cos2[u] = (float)cos(ang);
    sin2[u] = (float)sin(ang);
  }
}

// ---------------------------------------------------------------- fp32 -> bf16
__global__ __launch_bounds__(256) void f32_to_bf16(
    const float* __restrict__ src, unsigned short* __restrict__ dst, int n4) {
  int i = blockIdx.x * 256 + threadIdx.x;
  if (i < n4) {
    float4 v = ((const float4*)src)[i];
    unsigned short t[4] = {f2bf(v.x), f2bf(v.y), f2bf(v.z), f2bf(v.w)};
    ((short4v*)dst)[i] = *(short4v*)t;
  }
}

// all four 1024x1024 weights in one launch (blockIdx.y selects the matrix)
__global__ __launch_bounds__(256) void w4_to_bf16(
    const float* __restrict__ w0, const float* __restrict__ w1,
    const float* __restrict__ w2, const float* __restrict__ w3,
    unsigned short* __restrict__ dst) {
  const float* srcs[4] = {w0, w1, w2, w3};
  const float* src = srcs[blockIdx.y];
  unsigned short* d = dst + (size_t)blockIdx.y * D_ * D_;
  int i = blockIdx.x * 256 + threadIdx.x;   // < D_*D_/4
  float4 v = ((const float4*)src)[i];
  unsigned short t[4] = {f2bf(v.x), f2bf(v.y), f2bf(v.z), f2bf(v.w)};
  ((short4v*)d)[i] = *(short4v*)t;
}

// ---------------------------------------------------------------- bf16 MFMA GEMM
// C[M,1024] = A[M,1024] @ W[1024,1024]^T + bias.  m97 structure: 128x128 tile,
// BK=32, global_load_lds dwordx4 staging, 8 ds_read_b128 + 16 MFMA /wave/K-step.
template <bool BF16OUT>
__global__ __launch_bounds__(256) void gemm_mfma(
    const unsigned short* __restrict__ A, const unsigned short* __restrict__ W,
    const float* __restrict__ bias, void* __restrict__ Cout) {
  __shared__ unsigned short As[128 * 32];   // [row][k] contiguous, no pad (m104)
  __shared__ unsigned short Bs[128 * 32];
  const int t = threadIdx.x;
  const int w = t >> 6, L = t & 63;
  const int c = L & 15, g = L >> 4;
  const int id = blockIdx.x;
  const int xcd = id & 7, slot = id >> 3;
  const int bn = (slot & 7) * 128;
  const int bm = ((slot >> 3) * 8 + xcd) * 128;

  const int srow = w * 32 + (L >> 2);
  const int sko = (L & 3) * 8;
  const unsigned short* gA = A + (size_t)(bm + srow) * D_ + sko;
  const unsigned short* gB = W + (size_t)(bn + srow) * D_ + sko;
  unsigned short* lA = As + w * 1024;
  unsigned short* lB = Bs + w * 1024;

  const int wm = (w >> 1) * 64, wn = (w & 1) * 64;

  float4v acc[4][4];
#pragma unroll
  for (int i = 0; i < 4; ++i)
#pragma unroll
    for (int j = 0; j < 4; ++j) acc[i][j] = (float4v){0.f, 0.f, 0.f, 0.f};

  for (int k0 = 0; k0 < D_; k0 += 32) {
    __syncthreads();
    load_lds16(gA + k0, lA);
    load_lds16(gA + k0 + 16 * D_, lA + 512);
    load_lds16(gB + k0, lB);
    load_lds16(gB + k0 + 16 * D_, lB + 512);
    __syncthreads();
    short8v af[4], bf[4];
#pragma unroll
    for (int i = 0; i < 4; ++i)
      af[i] = *(const short8v*)&As[(wm + 16 * i + c) * 32 + 8 * g];
#pragma unroll
    for (int j = 0; j < 4; ++j)
      bf[j] = *(const short8v*)&Bs[(wn + 16 * j + c) * 32 + 8 * g];
#pragma unroll
    for (int i = 0; i < 4; ++i)
#pragma unroll
      for (int j = 0; j < 4; ++j)
        acc[i][j] = __builtin_amdgcn_mfma_f32_16x16x32_bf16(af[i], bf[j], acc[i][j], 0, 0, 0);
  }
#pragma unroll
  for (int i = 0; i < 4; ++i)
#pragma unroll
    for (int r = 0; r < 4; ++r) {
      const size_t row = (size_t)bm + wm + 16 * i + 4 * g + r;
#pragma unroll
      for (int j = 0; j < 4; ++j) {
        const int col = bn + wn + 16 * j + c;
        float vv = acc[i][j][r] + bias[col];
        if (BF16OUT)
          ((unsigned short*)Cout)[row * D_ + col] = f2bf(vv);
        else
          ((float*)Cout)[row * D_ + col] = vv;
      }
    }
}

// ---------------------------------------------------------------- RoPE in place (bf16)
__global__ __launch_bounds__(256) void rope_inplace(
    unsigned short* q,
    const float* __restrict__ cos1, const float* __restrict__ sin1,
    const float* __restrict__ cos2, const float* __restrict__ sin2,
    float scale) {
  int tid = blockIdx.x * 256 + threadIdx.x;
  int u = tid & 511;
  int m = tid >> 9;
  int s = m & (S_ - 1);
  int head = u >> 5, w = u & 31;
  size_t base = (size_t)m * D_ + head * 64;
  size_t c0, c1;
  float cv, sv;
  if (w < 8) {
    c0 = base + 2 * w; c1 = c0 + 1;
    cv = cos1[s * 8 + w]; sv = sin1[s * 8 + w];
  } else if (w < 20) {
    int j = w - 8, x = s & 31;
    c0 = base + 16 + j; c1 = base + 28 + j;
    cv = cos2[x * 12 + j]; sv = sin2[x * 12 + j];
  } else {
    int j = w - 20, y = s >> 5;
    c0 = base + 40 + j; c1 = base + 52 + j;
    cv = cos2[y * 12 + j]; sv = sin2[y * 12 + j];
  }
  float a = bf2f(q[c0]), b = bf2f(q[c1]);
  q[c0] = f2bf((a * cv - b * sv) * scale);
  q[c1] = f2bf((a * sv + b * cv) * scale);
}

// ---------------------------------------------------------------- V transpose (bf16)
// vb [b][s][head*64+n]  ->  vT [b][head][n(64)][s(1024)]
__global__ __launch_bounds__(256) void v_transpose(
    const unsigned short* __restrict__ v, unsigned short* __restrict__ vT) {
  __shared__ unsigned short T[64][72];
  const int t = threadIdx.x;
  const int st0 = blockIdx.x * 64;
  const int hd = blockIdx.y, b = blockIdx.z;
  const unsigned short* src = v + ((size_t)b * S_ + st0) * D_ + hd * 64;
#pragma unroll
  for (int rep = 0; rep < 4; ++rep) {
    int id = t + rep * 256;
    int s = id >> 4, n4 = (id & 15) * 4;
    short4v val = *(const short4v*)(src + (size_t)s * D_ + n4);
    T[n4 + 0][s] = val[0]; T[n4 + 1][s] = val[1];
    T[n4 + 2][s] = val[2]; T[n4 + 3][s] = val[3];
  }
  __syncthreads();
  unsigned short* dst = vT + ((size_t)(b * NH_ + hd) * 64) * S_ + st0;
#pragma unroll
  for (int rep = 0; rep < 2; ++rep) {
    int id = t + rep * 256;
    int n = id >> 3, s8 = (id & 7) * 8;
    unsigned short tmp[8];
#pragma unroll
    for (int u2 = 0; u2 < 8; ++u2) tmp[u2] = T[n][s8 + u2];
    *(short8v*)(dst + (size_t)n * S_ + s8) = *(short8v*)tmp;
  }
}

// ---------------------------------------------------------------- MFMA flash attention
// grid = 2048 linear, swizzled: xcd=id%8, slot=id/8, qt=slot%8,
// pair=(slot/8)*8+xcd.  8 qt-blocks of a pair sit on ONE XCD -> K/V L2-resident.
//
// Round-4 structure: rounds 0-3 invariance (dur 258+-2us across 3 inner-loop
// rewrites, VGPR 92-128, LDS 0-18KB; occupancy pinned 22%) -> limiter is the
// per-wave redundant global K/V load stream (4 waves x 16 dwordx4/tile, each
// touching 16 2KB-strided lines -> L1 thrash + per-CU miss-parallelism wall).
// Fix: block-shared double-buffered LDS staging via global_load_lds (16
// insts/block/tile, 4x fewer), 2-phase pipeline (stage kt+1 || compute kt,
// one vmcnt(0)+barrier per tile).  Both tiles are [64 rows][128B] read as
// ds_read_b128 per row == the 32-way-conflict geometry, so apply the G4 XOR
// swizzle byte^=((row&7)<<4) via rule #21: linear LDS dest + inverse-swizzled
// GLOBAL source lane address + swizzled read offset.
__global__ __launch_bounds__(256, 4) void attn_mfma(
    const unsigned short* __restrict__ qb, const unsigned short* __restrict__ kb,
    const unsigned short* __restrict__ vT, unsigned short* __restrict__ out) {
  __shared__ unsigned short KV[2][2][4096];   // [dbuf][K/V][64 rows x 64 elems]
  const int t = threadIdx.x;
  const int w = t >> 6;
  const int L = t & 63;
  const int c = L & 15;
  const int g = L >> 4;
  const int id = blockIdx.x;
  const int xcd = id & 7, slot = id >> 3;
  const int qt = slot & 7;
  const int pair = (slot >> 3) * 8 + xcd;
  const int b = pair >> 4, hd = pair & 15;
  const size_t mrow0 = (size_t)b * S_ + qt * 128 + w * 32;
  const int dcol0 = hd * 64;

  // staging lane geometry: lane L writes LDS bytes [seg*1024 + L*16, +16);
  // that LDS slot logically holds tile row seg*8+(L>>3), col-chunk (L&7);
  // inverse-swizzle the SOURCE col-chunk so reads can XOR with ((row&7)<<4).
  const int lrow = L >> 3;                        // row within 8-row segment
  const int lcol = ((L & 7) ^ lrow) * 8;          // source col offset (elems)

  // bpermute pull addresses (byte = 4*src_lane)
  const int a_lo = (((L & 16) ? 32 : 0) + c) * 4; // src g = 2*(g&1)
  const int a_hi = a_lo + 64;                     // src g = 2*(g&1)+1
  const bool ghi = (L >= 32);                     // g>=2 -> wants upper jl
  const int swz = (c & 7) << 3;                   // read-side XOR (elems)

  short8v aq[2][2];
#pragma unroll
  for (int i = 0; i < 2; ++i)
#pragma unroll
    for (int st = 0; st < 2; ++st)
      aq[i][st] = *(const short8v*)(qb + (mrow0 + 16 * i + c) * D_ + dcol0 + 32 * st + 8 * g);

  float4v oacc[2][4];
  float lsum[2] = {0.f, 0.f};
#pragma unroll
  for (int i = 0; i < 2; ++i)
#pragma unroll
    for (int jv = 0; jv < 4; ++jv) oacc[i][jv] = (float4v){0.f, 0.f, 0.f, 0.f};

  const unsigned short* vbase = vT + (size_t)(b * NH_ + hd) * 64 * S_;
  const unsigned short* kbb = kb + (size_t)b * S_ * D_ + dcol0;

  // stage one K/V tile pair into KV[buf]; wave w covers segments 2w, 2w+1
#define STAGE(buf, kt_)                                                          \
  {                                                                              \
    _Pragma("unroll")                                                            \
    for (int e = 0; e < 2; ++e) {                                                \
      const int seg = 2 * w + e;                                                 \
      const int row = seg * 8 + lrow;                                            \
      load_lds16(kbb + (size_t)((kt_) * 64 + row) * D_ + lcol,                   \
                 &KV[buf][0][seg * 512]);                                        \
      load_lds16(vbase + (size_t)row * S_ + (kt_) * 64 + lcol,                   \
                 &KV[buf][1][seg * 512]);                                        \
    }                                                                            \
  }

  STAGE(0, 0);
  asm volatile("s_waitcnt vmcnt(0)" ::: "memory");
  __syncthreads();

#pragma unroll 1
  for (int kt = 0; kt < 16; ++kt) {
    const int cur = kt & 1;
    if (kt < 15) STAGE(cur ^ 1, kt + 1);
#pragma unroll
    for (int st = 0; st < 2; ++st) {
      // V fragments for this half from LDS (swizzled read)
      short8v vfh[4];
#pragma unroll
      for (int jv = 0; jv < 4; ++jv)
        vfh[jv] = *(const short8v*)&KV[cur][1][((16 * jv + c) * 64 + st * 32 + 8 * g) ^ swz];
      // K fragments: k-rows 32*st..+31 (j = 2st+jl), d-halves h
      short8v kfh[2][2];
#pragma unroll
      for (int jl = 0; jl < 2; ++jl)
#pragma unroll
        for (int h = 0; h < 2; ++h)
          kfh[jl][h] = *(const short8v*)&KV[cur][0][((16 * (2 * st + jl) + c) * 64 + h * 32 + 8 * g) ^ swz];
      // QK half: sacch[i][jl] = S^T for k-rows 16*(2st+jl)..+15
      float4v sacch[2][2];
#pragma unroll
      for (int i = 0; i < 2; ++i)
#pragma unroll
        for (int jl = 0; jl < 2; ++jl) sacch[i][jl] = (float4v){0.f, 0.f, 0.f, 0.f};
      __builtin_amdgcn_s_setprio(1);
#pragma unroll
      for (int jl = 0; jl < 2; ++jl)
#pragma unroll
        for (int i = 0; i < 2; ++i) {
          sacch[i][jl] = __builtin_amdgcn_mfma_f32_16x16x32_bf16(kfh[jl][0], aq[i][0], sacch[i][jl], 0, 0, 0);
          sacch[i][jl] = __builtin_amdgcn_mfma_f32_16x16x32_bf16(kfh[jl][1], aq[i][1], sacch[i][jl], 0, 0, 0);
        }
      __builtin_amdgcn_s_setprio(0);
      // in-register softmax: exp + lane-local row-sum + pack pairs to bf16 (RNE)
      unsigned pkh[2][2][2];
#pragma unroll
      for (int i = 0; i < 2; ++i)
#pragma unroll
        for (int jl = 0; jl < 2; ++jl) {
          float p0 = __expf(sacch[i][jl][0]);
          float p1 = __expf(sacch[i][jl][1]);
          float p2 = __expf(sacch[i][jl][2]);
          float p3 = __expf(sacch[i][jl][3]);
          lsum[i] += (p0 + p1) + (p2 + p3);
          pkh[i][jl][0] = pack2bf(p0, p1);
          pkh[i][jl][1] = pack2bf(p2, p3);
        }
      // redistribute: aph[i] elem 8g+u = P[q=16i+c][k=32st+8g+u]
      short8v aph[2];
#pragma unroll
      for (int i = 0; i < 2; ++i) {
        uint4v wv;
#pragma unroll
        for (int q2 = 0; q2 < 4; ++q2) {
          const int addr = (q2 & 2) ? a_hi : a_lo;
          int vlo = __builtin_amdgcn_ds_bpermute(addr, (int)pkh[i][0][q2 & 1]);
          int vhi = __builtin_amdgcn_ds_bpermute(addr, (int)pkh[i][1][q2 & 1]);
          wv[q2] = (unsigned)(ghi ? vhi : vlo);
        }
        aph[i] = *(short8v*)&wv;
      }
      // PV half: accumulate this st's k-contribution
      __builtin_amdgcn_s_setprio(1);
#pragma unroll
      for (int jv = 0; jv < 4; ++jv)
#pragma unroll
        for (int i = 0; i < 2; ++i)
          oacc[i][jv] = __builtin_amdgcn_mfma_f32_16x16x32_bf16(aph[i], vfh[jv], oacc[i][jv], 0, 0, 0);
      __builtin_amdgcn_s_setprio(0);
    }
    // staged kt+1 fully in LDS + all waves done reading buf cur
    asm volatile("s_waitcnt vmcnt(0)" ::: "memory");
    __syncthreads();
  }
#undef STAGE
#pragma unroll
  for (int i = 0; i < 2; ++i) {
    float ls = lsum[i];
    ls += __shfl_xor(ls, 16);
    ls += __shfl_xor(ls, 32);
#pragma unroll
    for (int r = 0; r < 4; ++r) {
      // output row q=16i+4g+r; its denominator lives at lane 4g+r
      float inv = 1.f / __shfl(ls, 4 * g + r);
      size_t row = mrow0 + 16 * i + 4 * g + r;
#pragma unroll
      for (int jv = 0; jv < 4; ++jv)
        out[row * D_ + dcol0 + 16 * jv + c] = f2bf(oacc[i][jv][r] * inv);
    }
  }
}

// ---------------------------------------------------------------- launch
// Workspace (peak 168.03 MB < 192 MB proven):
//   [0,32)MB xb (reused as ob after QKV gemms) | [32,64) qb | [64,96) kb
//   [96,128) vb | [128,160) vT | [160,168) wqb,wkb,wvb,wob | [168,+32KB) tables
extern "C" void kernel_launch(void* const* d_in, const int* in_sizes, int n_in,
                              void* d_out, int out_size, void* d_ws, size_t ws_size,
                              hipStream_t stream) {
  const float* x  = (const float*)d_in[0];
  const float* Wq = (const float*)d_in[1];
  const float* bq = (const float*)d_in[2];
  const float* Wk = (const float*)d_in[3];
  const float* bk = (const float*)d_in[4];
  const float* Wv = (const float*)d_in[5];
  const float* bv = (const float*)d_in[6];
  const float* Wo = (const float*)d_in[7];
  const float* bo = (const float*)d_in[8];
  float* out = (float*)d_out;

  char* ws = (char*)d_ws;
  const size_t SZ2 = (size_t)M_TOT * D_ * 2;   // 32 MB
  unsigned short* xb = (unsigned short*)(ws);
  unsigned short* ob = xb;                               // alias: free after QKV gemms
  unsigned short* qb = (unsigned short*)(ws + SZ2);
  unsigned short* kb = (unsigned short*)(ws + 2 * SZ2);
  unsigned short* vb = (unsigned short*)(ws + 3 * SZ2);
  unsigned short* vT = (unsigned short*)(ws + 4 * SZ2);
  unsigned short* wqb = (unsigned short*)(ws + 5 * SZ2);
  unsigned short* wkb = wqb + (size_t)D_ * D_;
  unsigned short* wvb = wkb + (size_t)D_ * D_;
  unsigned short* wob = wvb + (size_t)D_ * D_;
  float* cos1 = (float*)(ws + 5 * SZ2 + 4 * (size_t)D_ * D_ * 2);
  float* sin1 = cos1 + S_ * 8;
  float* cos2 = sin1 + S_ * 8;
  float* sin2 = cos2 + 384;

  build_tables<<<34, 256, 0, stream>>>(cos1, sin1, cos2, sin2);

  f32_to_bf16<<<M_TOT * D_ / 4 / 256, 256, 0, stream>>>(x, xb, M_TOT * D_ / 4);
  w4_to_bf16<<<dim3(D_ * D_ / 4 / 256, 4), 256, 0, stream>>>(Wq, Wk, Wv, Wo, wqb);

  gemm_mfma<true><<<1024, 256, 0, stream>>>(xb, wqb, bq, qb);
  gemm_mfma<true><<<1024, 256, 0, stream>>>(xb, wkb, bk, kb);
  gemm_mfma<true><<<1024, 256, 0, stream>>>(xb, wvb, bv, vb);

  const int rope_blocks = (M_TOT * 512) / 256;
  rope_inplace<<<rope_blocks, 256, 0, stream>>>(qb, cos1, sin1, cos2, sin2, 0.125f);
  rope_inplace<<<rope_blocks, 256, 0, stream>>>(kb, cos1, sin1, cos2, sin2, 1.0f);
  v_transpose<<<dim3(16, 16, 16), 256, 0, stream>>>(vb, vT);

  attn_mfma<<<2048, 256, 0, stream>>>(qb, kb, vT, ob);

  gemm_mfma<false><<<1024, 256, 0, stream>>>(ob, wob, bo, out);
}

// Round 6
// 485.355 us; speedup vs baseline: 1.2635x; 1.0125x over previous
//
#include <hip/hip_runtime.h>
#include <math.h>

#define B_ 16
#define S_ 1024
#define D_ 1024
#define NH_ 16
#define M_TOT (B_ * S_)

typedef __attribute__((ext_vector_type(8))) short short8v;
typedef __attribute__((ext_vector_type(4))) short short4v;
typedef __attribute__((ext_vector_type(4))) float float4v;
typedef __attribute__((ext_vector_type(4))) unsigned int uint4v;

static __device__ __forceinline__ unsigned short f2bf(float f) {
  union { float f; unsigned u; } x; x.f = f;
  unsigned r = (x.u + 0x7fffu + ((x.u >> 16) & 1u)) >> 16;
  return (unsigned short)r;
}
static __device__ __forceinline__ float bf2f(unsigned short u) {
  union { unsigned u; float f; } x; x.u = ((unsigned)u) << 16;
  return x.f;
}

// pack two f32 -> bf16x2 word, RNE (a -> low half).  Manual f2bf (known-RNE);
// v_cvt_pk_bf16_f32 failed accuracy in round 1 (rounding-mode mismatch).
static __device__ __forceinline__ unsigned pack2bf(float a, float b) {
  return ((unsigned)f2bf(b) << 16) | (unsigned)f2bf(a);
}

// async global->LDS, 16B per lane; LDS dest = wave-uniform base + lane*16 (m104)
static __device__ __forceinline__ void load_lds16(const unsigned short* g, unsigned short* l) {
  __builtin_amdgcn_global_load_lds(
      (const __attribute__((address_space(1))) unsigned int*)g,
      (__attribute__((address_space(3))) unsigned int*)l, 16, 0, 0);
}

// ---------------------------------------------------------------- fused prep
// [0, 16384)        : x f32 -> bf16 (4 elems/thread)
// [16384, 20480)    : 4 weight matrices f32 -> bf16 (4 elems/thread)
// [20480, 20514)    : RoPE tables
__global__ __launch_bounds__(256) void prep(
    const float* __restrict__ x, unsigned short* __restrict__ xb,
    const float* __restrict__ w0, const float* __restrict__ w1,
    const float* __restrict__ w2, const float* __restrict__ w3,
    unsigned short* __restrict__ wdst,
    float* __restrict__ cos1, float* __restrict__ sin1,
    float* __restrict__ cos2, float* __restrict__ sin2) {
  const int bid = blockIdx.x;
  if (bid < 16384) {
    int i = bid * 256 + threadIdx.x;       // < M_TOT*D_/4
    float4 v = ((const float4*)x)[i];
    unsigned short tt[4] = {f2bf(v.x), f2bf(v.y), f2bf(v.z), f2bf(v.w)};
    ((short4v*)xb)[i] = *(short4v*)tt;
  } else if (bid < 20480) {
    int wi = (bid - 16384) * 256 + threadIdx.x;   // < 4*D_*D_/4
    int m = wi >> 18;                             // matrix (block-uniform)
    int i = wi & 262143;
    const float* src = (m == 0) ? w0 : (m == 1) ? w1 : (m == 2) ? w2 : w3;
    float4 v = ((const float4*)src)[i];
    unsigned short tt[4] = {f2bf(v.x), f2bf(v.y), f2bf(v.z), f2bf(v.w)};
    ((short4v*)(wdst + (size_t)m * D_ * D_))[i] = *(short4v*)tt;
  } else {
    int t = (bid - 20480) * 256 + threadIdx.x;
    if (t < S_ * 8) {
      int s = t >> 3, i = t & 7;
      double ang = (double)s * pow(10000.0, -(double)i / 8.0);
      cos1[t] = (float)cos(ang);
      sin1[t] = (float)sin(ang);
    } else if (t < S_ * 8 + 384) {
      int u = t - S_ * 8;
      int p = u / 12, j = u - p * 12;
      double ang = (double)p * pow(10000.0, -(double)j / 12.0);
      cos2[u] = (float)cos(ang);
      sin2[u] = (float)sin(ang);
    }
  }
}

// ---------------------------------------------------------------- bf16 MFMA GEMM
// C[M,1024] = A[M,1024] @ W[1024,1024]^T + bias.  128x128 tile, BK=32,
// global_load_lds staging, 2-phase double-buffered: stage k0+32 into buf^1
// BEFORE computing buf, EXPLICIT vmcnt(0) drain + one barrier per K-step
// (explicit drain mirrors the proven attn pattern; round-5 relied on the
// implicit barrier drain and failed accuracy -- do not trust it).
// grid.y selects {W, bias, C} (QKV fused into one launch; O uses y=0).
template <bool BF16OUT>
__global__ __launch_bounds__(256) void gemm_mfma(
    const unsigned short* __restrict__ A, const unsigned short* __restrict__ Wall,
    const float* __restrict__ b0, const float* __restrict__ b1,
    const float* __restrict__ b2, void* __restrict__ Cout) {
  __shared__ unsigned short As[2][128 * 32];
  __shared__ unsigned short Bs[2][128 * 32];
  const int y = blockIdx.y;
  const unsigned short* W = Wall + (size_t)y * D_ * D_;
  const float* bias = (y == 0) ? b0 : (y == 1) ? b1 : b2;
  const int t = threadIdx.x;
  const int w = t >> 6, L = t & 63;
  const int c = L & 15, g = L >> 4;
  const int id = blockIdx.x;
  const int xcd = id & 7, slot = id >> 3;
  const int bn = (slot & 7) * 128;
  const int bm = ((slot >> 3) * 8 + xcd) * 128;

  const int srow = w * 32 + (L >> 2);
  const int sko = (L & 3) * 8;
  const unsigned short* gA = A + (size_t)(bm + srow) * D_ + sko;
  const unsigned short* gB = W + (size_t)(bn + srow) * D_ + sko;

  const int wm = (w >> 1) * 64, wn = (w & 1) * 64;

  float4v acc[4][4];
#pragma unroll
  for (int i = 0; i < 4; ++i)
#pragma unroll
    for (int j = 0; j < 4; ++j) acc[i][j] = (float4v){0.f, 0.f, 0.f, 0.f};

#define GS(buf, k0_)                                                  \
  {                                                                   \
    load_lds16(gA + (k0_), &As[buf][w * 1024]);                       \
    load_lds16(gA + (k0_) + 16 * D_, &As[buf][w * 1024 + 512]);       \
    load_lds16(gB + (k0_), &Bs[buf][w * 1024]);                       \
    load_lds16(gB + (k0_) + 16 * D_, &Bs[buf][w * 1024 + 512]);       \
  }

  GS(0, 0);
  asm volatile("s_waitcnt vmcnt(0)" ::: "memory");
  __syncthreads();
  int cur = 0;
  for (int k0 = 0; k0 < D_; k0 += 32) {
    if (k0 + 32 < D_) GS(cur ^ 1, k0 + 32);
    short8v af[4], bf[4];
#pragma unroll
    for (int i = 0; i < 4; ++i)
      af[i] = *(const short8v*)&As[cur][(wm + 16 * i + c) * 32 + 8 * g];
#pragma unroll
    for (int j = 0; j < 4; ++j)
      bf[j] = *(const short8v*)&Bs[cur][(wn + 16 * j + c) * 32 + 8 * g];
#pragma unroll
    for (int i = 0; i < 4; ++i)
#pragma unroll
      for (int j = 0; j < 4; ++j)
        acc[i][j] = __builtin_amdgcn_mfma_f32_16x16x32_bf16(af[i], bf[j], acc[i][j], 0, 0, 0);
    // staging writes for buf^1 landed + all waves done reading buf cur
    asm volatile("s_waitcnt vmcnt(0)" ::: "memory");
    __syncthreads();
    cur ^= 1;
  }
#undef GS
  unsigned short* Cb = (unsigned short*)Cout + (size_t)y * M_TOT * D_;
#pragma unroll
  for (int i = 0; i < 4; ++i)
#pragma unroll
    for (int r = 0; r < 4; ++r) {
      const size_t row = (size_t)bm + wm + 16 * i + 4 * g + r;
#pragma unroll
      for (int j = 0; j < 4; ++j) {
        const int col = bn + wn + 16 * j + c;
        float vv = acc[i][j][r] + bias[col];
        if (BF16OUT)
          Cb[row * D_ + col] = f2bf(vv);
        else
          ((float*)Cout)[row * D_ + col] = vv;
      }
    }
}

// ---------------------------------------------------------------- fused postproc
// [0, 32768)      : RoPE on Q (scale 0.125)
// [32768, 65536)  : RoPE on K (scale 1.0)
// [65536, 69632)  : V transpose vb [b][s][hd*64+n] -> vT [b][hd][n][s]
__global__ __launch_bounds__(256) void postproc(
    unsigned short* __restrict__ qb, unsigned short* __restrict__ kbuf,
    const unsigned short* __restrict__ vb, unsigned short* __restrict__ vT,
    const float* __restrict__ cos1, const float* __restrict__ sin1,
    const float* __restrict__ cos2, const float* __restrict__ sin2) {
  __shared__ unsigned short T[64][72];
  const int bid = blockIdx.x;
  if (bid < 65536) {
    unsigned short* q = (bid < 32768) ? qb : kbuf;
    const float scale = (bid < 32768) ? 0.125f : 1.0f;
    int tid = (bid & 32767) * 256 + threadIdx.x;
    int u = tid & 511;
    int m = tid >> 9;
    int s = m & (S_ - 1);
    int head = u >> 5, w = u & 31;
    size_t base = (size_t)m * D_ + head * 64;
    size_t c0, c1;
    float cv, sv;
    if (w < 8) {
      c0 = base + 2 * w; c1 = c0 + 1;
      cv = cos1[s * 8 + w]; sv = sin1[s * 8 + w];
    } else if (w < 20) {
      int j = w - 8, x = s & 31;
      c0 = base + 16 + j; c1 = base + 28 + j;
      cv = cos2[x * 12 + j]; sv = sin2[x * 12 + j];
    } else {
      int j = w - 20, yy = s >> 5;
      c0 = base + 40 + j; c1 = base + 52 + j;
      cv = cos2[yy * 12 + j]; sv = sin2[yy * 12 + j];
    }
    float a = bf2f(q[c0]), b = bf2f(q[c1]);
    q[c0] = f2bf((a * cv - b * sv) * scale);
    q[c1] = f2bf((a * sv + b * cv) * scale);
  } else {
    const int tb = bid - 65536;            // < 4096 = 16 st * 16 hd * 16 b
    const int t = threadIdx.x;
    const int st0 = (tb & 15) * 64;
    const int hd = (tb >> 4) & 15, b = tb >> 8;
    const unsigned short* src = vb + ((size_t)b * S_ + st0) * D_ + hd * 64;
#pragma unroll
    for (int rep = 0; rep < 4; ++rep) {
      int id = t + rep * 256;
      int s = id >> 4, n4 = (id & 15) * 4;
      short4v val = *(const short4v*)(src + (size_t)s * D_ + n4);
      T[n4 + 0][s] = val[0]; T[n4 + 1][s] = val[1];
      T[n4 + 2][s] = val[2]; T[n4 + 3][s] = val[3];
    }
    __syncthreads();
    unsigned short* dst = vT + ((size_t)(b * NH_ + hd) * 64) * S_ + st0;
#pragma unroll
    for (int rep = 0; rep < 2; ++rep) {
      int id = t + rep * 256;
      int n = id >> 3, s8 = (id & 7) * 8;
      unsigned short tmp[8];
#pragma unroll
      for (int u2 = 0; u2 < 8; ++u2) tmp[u2] = T[n][s8 + u2];
      *(short8v*)(dst + (size_t)n * S_ + s8) = *(short8v*)tmp;
    }
  }
}

// ---------------------------------------------------------------- MFMA flash attention
// grid = 2048 linear, swizzled: xcd=id%8, slot=id/8, qt=slot%8,
// pair=(slot/8)*8+xcd.  8 qt-blocks of a pair sit on ONE XCD -> K/V L2-resident.
// Block-shared double-buffered LDS K/V staging (round-4 2x win), swapped QK^T
// with in-register softmax, bpermute P-redistribution.  Byte-identical to the
// round-4 kernel that passed (exp2/log2e fold reverted pending attribution).
__global__ __launch_bounds__(256, 4) void attn_mfma(
    const unsigned short* __restrict__ qb, const unsigned short* __restrict__ kb,
    const unsigned short* __restrict__ vT, unsigned short* __restrict__ out) {
  __shared__ unsigned short KV[2][2][4096];   // [dbuf][K/V][64 rows x 64 elems]
  const int t = threadIdx.x;
  const int w = t >> 6;
  const int L = t & 63;
  const int c = L & 15;
  const int g = L >> 4;
  const int id = blockIdx.x;
  const int xcd = id & 7, slot = id >> 3;
  const int qt = slot & 7;
  const int pair = (slot >> 3) * 8 + xcd;
  const int b = pair >> 4, hd = pair & 15;
  const size_t mrow0 = (size_t)b * S_ + qt * 128 + w * 32;
  const int dcol0 = hd * 64;

  // staging lane geometry: lane L writes LDS bytes [seg*1024 + L*16, +16);
  // holds tile row seg*8+(L>>3), col-chunk (L&7); inverse-swizzle the SOURCE
  // col-chunk so reads can XOR with ((row&7)<<4)  (rule #21).
  const int lrow = L >> 3;
  const int lcol = ((L & 7) ^ lrow) * 8;

  // bpermute pull addresses (byte = 4*src_lane)
  const int a_lo = (((L & 16) ? 32 : 0) + c) * 4;
  const int a_hi = a_lo + 64;
  const bool ghi = (L >= 32);
  const int swz = (c & 7) << 3;                   // read-side XOR (elems)

  short8v aq[2][2];
#pragma unroll
  for (int i = 0; i < 2; ++i)
#pragma unroll
    for (int st = 0; st < 2; ++st)
      aq[i][st] = *(const short8v*)(qb + (mrow0 + 16 * i + c) * D_ + dcol0 + 32 * st + 8 * g);

  float4v oacc[2][4];
  float lsum[2] = {0.f, 0.f};
#pragma unroll
  for (int i = 0; i < 2; ++i)
#pragma unroll
    for (int jv = 0; jv < 4; ++jv) oacc[i][jv] = (float4v){0.f, 0.f, 0.f, 0.f};

  const unsigned short* vbase = vT + (size_t)(b * NH_ + hd) * 64 * S_;
  const unsigned short* kbb = kb + (size_t)b * S_ * D_ + dcol0;

#define STAGE(buf, kt_)                                                          \
  {                                                                              \
    _Pragma("unroll")                                                            \
    for (int e = 0; e < 2; ++e) {                                                \
      const int seg = 2 * w + e;                                                 \
      const int row = seg * 8 + lrow;                                            \
      load_lds16(kbb + (size_t)((kt_) * 64 + row) * D_ + lcol,                   \
                 &KV[buf][0][seg * 512]);                                        \
      load_lds16(vbase + (size_t)row * S_ + (kt_) * 64 + lcol,                   \
                 &KV[buf][1][seg * 512]);                                        \
    }                                                                            \
  }

  STAGE(0, 0);
  asm volatile("s_waitcnt vmcnt(0)" ::: "memory");
  __syncthreads();

#pragma unroll 1
  for (int kt = 0; kt < 16; ++kt) {
    const int cur = kt & 1;
    if (kt < 15) STAGE(cur ^ 1, kt + 1);
#pragma unroll
    for (int st = 0; st < 2; ++st) {
      short8v vfh[4];
#pragma unroll
      for (int jv = 0; jv < 4; ++jv)
        vfh[jv] = *(const short8v*)&KV[cur][1][((16 * jv + c) * 64 + st * 32 + 8 * g) ^ swz];
      short8v kfh[2][2];
#pragma unroll
      for (int jl = 0; jl < 2; ++jl)
#pragma unroll
        for (int h = 0; h < 2; ++h)
          kfh[jl][h] = *(const short8v*)&KV[cur][0][((16 * (2 * st + jl) + c) * 64 + h * 32 + 8 * g) ^ swz];
      float4v sacch[2][2];
#pragma unroll
      for (int i = 0; i < 2; ++i)
#pragma unroll
        for (int jl = 0; jl < 2; ++jl) sacch[i][jl] = (float4v){0.f, 0.f, 0.f, 0.f};
      __builtin_amdgcn_s_setprio(1);
#pragma unroll
      for (int jl = 0; jl < 2; ++jl)
#pragma unroll
        for (int i = 0; i < 2; ++i) {
          sacch[i][jl] = __builtin_amdgcn_mfma_f32_16x16x32_bf16(kfh[jl][0], aq[i][0], sacch[i][jl], 0, 0, 0);
          sacch[i][jl] = __builtin_amdgcn_mfma_f32_16x16x32_bf16(kfh[jl][1], aq[i][1], sacch[i][jl], 0, 0, 0);
        }
      __builtin_amdgcn_s_setprio(0);
      // in-register softmax: exp + lane-local row-sum + pack pairs to bf16 (RNE)
      unsigned pkh[2][2][2];
#pragma unroll
      for (int i = 0; i < 2; ++i)
#pragma unroll
        for (int jl = 0; jl < 2; ++jl) {
          float p0 = __expf(sacch[i][jl][0]);
          float p1 = __expf(sacch[i][jl][1]);
          float p2 = __expf(sacch[i][jl][2]);
          float p3 = __expf(sacch[i][jl][3]);
          lsum[i] += (p0 + p1) + (p2 + p3);
          pkh[i][jl][0] = pack2bf(p0, p1);
          pkh[i][jl][1] = pack2bf(p2, p3);
        }
      short8v aph[2];
#pragma unroll
      for (int i = 0; i < 2; ++i) {
        uint4v wv;
#pragma unroll
        for (int q2 = 0; q2 < 4; ++q2) {
          const int addr = (q2 & 2) ? a_hi : a_lo;
          int vlo = __builtin_amdgcn_ds_bpermute(addr, (int)pkh[i][0][q2 & 1]);
          int vhi = __builtin_amdgcn_ds_bpermute(addr, (int)pkh[i][1][q2 & 1]);
          wv[q2] = (unsigned)(ghi ? vhi : vlo);
        }
        aph[i] = *(short8v*)&wv;
      }
      __builtin_amdgcn_s_setprio(1);
#pragma unroll
      for (int jv = 0; jv < 4; ++jv)
#pragma unroll
        for (int i = 0; i < 2; ++i)
          oacc[i][jv] = __builtin_amdgcn_mfma_f32_16x16x32_bf16(aph[i], vfh[jv], oacc[i][jv], 0, 0, 0);
      __builtin_amdgcn_s_setprio(0);
    }
    asm volatile("s_waitcnt vmcnt(0)" ::: "memory");
    __syncthreads();
  }
#undef STAGE
#pragma unroll
  for (int i = 0; i < 2; ++i) {
    float ls = lsum[i];
    ls += __shfl_xor(ls, 16);
    ls += __shfl_xor(ls, 32);
#pragma unroll
    for (int r = 0; r < 4; ++r) {
      float inv = 1.f / __shfl(ls, 4 * g + r);
      size_t row = mrow0 + 16 * i + 4 * g + r;
#pragma unroll
      for (int jv = 0; jv < 4; ++jv)
        out[row * D_ + dcol0 + 16 * jv + c] = f2bf(oacc[i][jv][r] * inv);
    }
  }
}

// ---------------------------------------------------------------- launch
// Workspace (peak 168.03 MB < 192 MB proven):
//   [0,32)MB xb (reused as ob after QKV gemms) | [32,64) qb | [64,96) kb
//   [96,128) vb | [128,160) vT | [160,168) wqb..wob | [168,+32KB) tables
extern "C" void kernel_launch(void* const* d_in, const int* in_sizes, int n_in,
                              void* d_out, int out_size, void* d_ws, size_t ws_size,
                              hipStream_t stream) {
  const float* x  = (const float*)d_in[0];
  const float* Wq = (const float*)d_in[1];
  const float* bq = (const float*)d_in[2];
  const float* Wk = (const float*)d_in[3];
  const float* bk = (const float*)d_in[4];
  const float* Wv = (const float*)d_in[5];
  const float* bv = (const float*)d_in[6];
  const float* Wo = (const float*)d_in[7];
  const float* bo = (const float*)d_in[8];
  float* out = (float*)d_out;

  char* ws = (char*)d_ws;
  const size_t SZ2 = (size_t)M_TOT * D_ * 2;   // 32 MB
  unsigned short* xb = (unsigned short*)(ws);
  unsigned short* ob = xb;                               // alias: free after QKV gemms
  unsigned short* qb = (unsigned short*)(ws + SZ2);
  unsigned short* kb = (unsigned short*)(ws + 2 * SZ2);
  unsigned short* vb = (unsigned short*)(ws + 3 * SZ2);
  unsigned short* vT = (unsigned short*)(ws + 4 * SZ2);
  unsigned short* wqb = (unsigned short*)(ws + 5 * SZ2);
  unsigned short* wob = wqb + 3 * (size_t)D_ * D_;
  float* cos1 = (float*)(ws + 5 * SZ2 + 4 * (size_t)D_ * D_ * 2);
  float* sin1 = cos1 + S_ * 8;
  float* cos2 = sin1 + S_ * 8;
  float* sin2 = cos2 + 384;

  // 1) tables + x->bf16 + 4 weights->bf16
  prep<<<20514, 256, 0, stream>>>(x, xb, Wq, Wk, Wv, Wo, wqb,
                                  cos1, sin1, cos2, sin2);
  // 2) Q,K,V projections in one launch (grid.y selects W/bias/output)
  gemm_mfma<true><<<dim3(1024, 3), 256, 0, stream>>>(xb, wqb, bq, bk, bv, qb);
  // 3) ropeQ + ropeK + V-transpose in one launch
  postproc<<<69632, 256, 0, stream>>>(qb, kb, vb, vT, cos1, sin1, cos2, sin2);
  // 4) attention
  attn_mfma<<<2048, 256, 0, stream>>>(qb, kb, vT, ob);
  // 5) output projection (f32 out)
  gemm_mfma<false><<<dim3(1024, 1), 256, 0, stream>>>(ob, wob, bo, bo, bo, out);
}

// Round 7
// 466.723 us; speedup vs baseline: 1.3140x; 1.0399x over previous
//
#include <hip/hip_runtime.h>
#include <math.h>

#define B_ 16
#define S_ 1024
#define D_ 1024
#define NH_ 16
#define M_TOT (B_ * S_)

typedef __attribute__((ext_vector_type(8))) short short8v;
typedef __attribute__((ext_vector_type(4))) short short4v;
typedef __attribute__((ext_vector_type(4))) float float4v;
typedef __attribute__((ext_vector_type(4))) unsigned int uint4v;

static __device__ __forceinline__ unsigned short f2bf(float f) {
  union { float f; unsigned u; } x; x.f = f;
  unsigned r = (x.u + 0x7fffu + ((x.u >> 16) & 1u)) >> 16;
  return (unsigned short)r;
}
static __device__ __forceinline__ float bf2f(unsigned short u) {
  union { unsigned u; float f; } x; x.u = ((unsigned)u) << 16;
  return x.f;
}

// pack two f32 -> bf16x2 word, RNE (a -> low half).  Manual f2bf (known-RNE);
// v_cvt_pk_bf16_f32 failed accuracy in round 1 (rounding-mode mismatch).
static __device__ __forceinline__ unsigned pack2bf(float a, float b) {
  return ((unsigned)f2bf(b) << 16) | (unsigned)f2bf(a);
}

// async global->LDS, 16B per lane; LDS dest = wave-uniform base + lane*16 (m104)
static __device__ __forceinline__ void load_lds16(const unsigned short* g, unsigned short* l) {
  __builtin_amdgcn_global_load_lds(
      (const __attribute__((address_space(1))) unsigned int*)g,
      (__attribute__((address_space(3))) unsigned int*)l, 16, 0, 0);
}

// ---------------------------------------------------------------- fused prep
// [0, 16384)        : x f32 -> bf16 (4 elems/thread)
// [16384, 20480)    : 4 weight matrices f32 -> bf16 (4 elems/thread)
// [20480, 20514)    : RoPE tables
__global__ __launch_bounds__(256) void prep(
    const float* __restrict__ x, unsigned short* __restrict__ xb,
    const float* __restrict__ w0, const float* __restrict__ w1,
    const float* __restrict__ w2, const float* __restrict__ w3,
    unsigned short* __restrict__ wdst,
    float* __restrict__ cos1, float* __restrict__ sin1,
    float* __restrict__ cos2, float* __restrict__ sin2) {
  const int bid = blockIdx.x;
  if (bid < 16384) {
    int i = bid * 256 + threadIdx.x;       // < M_TOT*D_/4
    float4 v = ((const float4*)x)[i];
    unsigned short tt[4] = {f2bf(v.x), f2bf(v.y), f2bf(v.z), f2bf(v.w)};
    ((short4v*)xb)[i] = *(short4v*)tt;
  } else if (bid < 20480) {
    int wi = (bid - 16384) * 256 + threadIdx.x;   // < 4*D_*D_/4
    int m = wi >> 18;                             // matrix (block-uniform)
    int i = wi & 262143;
    const float* src = (m == 0) ? w0 : (m == 1) ? w1 : (m == 2) ? w2 : w3;
    float4 v = ((const float4*)src)[i];
    unsigned short tt[4] = {f2bf(v.x), f2bf(v.y), f2bf(v.z), f2bf(v.w)};
    ((short4v*)(wdst + (size_t)m * D_ * D_))[i] = *(short4v*)tt;
  } else {
    int t = (bid - 20480) * 256 + threadIdx.x;
    if (t < S_ * 8) {
      int s = t >> 3, i = t & 7;
      double ang = (double)s * pow(10000.0, -(double)i / 8.0);
      cos1[t] = (float)cos(ang);
      sin1[t] = (float)sin(ang);
    } else if (t < S_ * 8 + 384) {
      int u = t - S_ * 8;
      int p = u / 12, j = u - p * 12;
      double ang = (double)p * pow(10000.0, -(double)j / 12.0);
      cos2[u] = (float)cos(ang);
      sin2[u] = (float)sin(ang);
    }
  }
}

// ---------------------------------------------------------------- bf16 MFMA GEMM
// C[M,1024] = A[M,1024] @ W[1024,1024]^T + bias.  128x128 tile, BK=32.
// Round-7 structure (T4, counted vmcnt): round-6's 2-phase drain-to-0 landed
// at 621 TF == m233's 607-TF stall anatomy (72% = stage+vmcnt(0)+barrier).
// Fix: 3 LDS buffers; per step: vmcnt(4) waits ONLY the current buffer's 4
// loads (next tile's 4 stay in flight across the barrier), raw s_barrier
// (NOT __syncthreads -- the compiler force-drains vmcnt(0) there), then
// stage k+2, then compute.  One barrier/step, drain-to-0 only at the last.
// Hazard audit: vmcnt retires in issue order, so <=4 outstanding => cur's
// loads landed; barrier at step t => all waves finished compute(t-1), so
// overwriting buf (t-1)%3 ( = (t+2)%3 ) at step t is safe.
// grid.y selects {W, bias, C} (QKV fused in one launch; O uses y=0).
template <bool BF16OUT>
__global__ __launch_bounds__(256) void gemm_mfma(
    const unsigned short* __restrict__ A, const unsigned short* __restrict__ Wall,
    const float* __restrict__ b0, const float* __restrict__ b1,
    const float* __restrict__ b2, void* __restrict__ Cout) {
  __shared__ unsigned short As[3][128 * 32];
  __shared__ unsigned short Bs[3][128 * 32];
  const int y = blockIdx.y;
  const unsigned short* W = Wall + (size_t)y * D_ * D_;
  const float* bias = (y == 0) ? b0 : (y == 1) ? b1 : b2;
  const int t = threadIdx.x;
  const int w = t >> 6, L = t & 63;
  const int c = L & 15, g = L >> 4;
  const int id = blockIdx.x;
  const int xcd = id & 7, slot = id >> 3;
  const int bn = (slot & 7) * 128;
  const int bm = ((slot >> 3) * 8 + xcd) * 128;

  const int srow = w * 32 + (L >> 2);
  const int sko = (L & 3) * 8;
  const unsigned short* gA = A + (size_t)(bm + srow) * D_ + sko;
  const unsigned short* gB = W + (size_t)(bn + srow) * D_ + sko;

  const int wm = (w >> 1) * 64, wn = (w & 1) * 64;

  float4v acc[4][4];
#pragma unroll
  for (int i = 0; i < 4; ++i)
#pragma unroll
    for (int j = 0; j < 4; ++j) acc[i][j] = (float4v){0.f, 0.f, 0.f, 0.f};

#define GS(buf, kt_)                                                   \
  {                                                                    \
    load_lds16(gA + (kt_) * 32, &As[buf][w * 1024]);                   \
    load_lds16(gA + (kt_) * 32 + 16 * D_, &As[buf][w * 1024 + 512]);   \
    load_lds16(gB + (kt_) * 32, &Bs[buf][w * 1024]);                   \
    load_lds16(gB + (kt_) * 32 + 16 * D_, &Bs[buf][w * 1024 + 512]);   \
  }
#define VWAIT4 asm volatile("s_waitcnt vmcnt(4)" ::: "memory")
#define VWAIT0 asm volatile("s_waitcnt vmcnt(0)" ::: "memory")
#define BARRIER asm volatile("s_barrier" ::: "memory")
#define COMPUTE(cur)                                                     \
  {                                                                      \
    short8v af[4], bf[4];                                                \
    _Pragma("unroll")                                                    \
    for (int i = 0; i < 4; ++i)                                          \
      af[i] = *(const short8v*)&As[cur][(wm + 16 * i + c) * 32 + 8 * g]; \
    _Pragma("unroll")                                                    \
    for (int j = 0; j < 4; ++j)                                          \
      bf[j] = *(const short8v*)&Bs[cur][(wn + 16 * j + c) * 32 + 8 * g]; \
    _Pragma("unroll")                                                    \
    for (int i = 0; i < 4; ++i)                                          \
      _Pragma("unroll")                                                  \
      for (int j = 0; j < 4; ++j)                                        \
        acc[i][j] = __builtin_amdgcn_mfma_f32_16x16x32_bf16(             \
            af[i], bf[j], acc[i][j], 0, 0, 0);                           \
  }

  GS(0, 0);          // outstanding 4
  GS(1, 1);          // outstanding 8
  // steps 0..29: stage k2..k31; s covers {0,3,..,27}; s+2<=29? no: s+2..s+4
  // are 2..31, all <32 for s<=27, so stages are unconditional.
#pragma unroll 1
  for (int s = 0; s < 30; s += 3) {
    VWAIT4; BARRIER; GS(2, s + 2); COMPUTE(0);   // step s
    VWAIT4; BARRIER; GS(0, s + 3); COMPUTE(1);   // step s+1
    VWAIT4; BARRIER; GS(1, s + 4); COMPUTE(2);   // step s+2
  }
  VWAIT4; BARRIER; COMPUTE(0);                   // step 30 (k30 in buf0)
  VWAIT0; BARRIER; COMPUTE(1);                   // step 31 (k31 in buf1)
#undef GS
#undef VWAIT4
#undef VWAIT0
#undef BARRIER
#undef COMPUTE
  unsigned short* Cb = (unsigned short*)Cout + (size_t)y * M_TOT * D_;
#pragma unroll
  for (int i = 0; i < 4; ++i)
#pragma unroll
    for (int r = 0; r < 4; ++r) {
      const size_t row = (size_t)bm + wm + 16 * i + 4 * g + r;
#pragma unroll
      for (int j = 0; j < 4; ++j) {
        const int col = bn + wn + 16 * j + c;
        float vv = acc[i][j][r] + bias[col];
        if (BF16OUT)
          Cb[row * D_ + col] = f2bf(vv);
        else
          ((float*)Cout)[row * D_ + col] = vv;
      }
    }
}

// ---------------------------------------------------------------- fused postproc
// [0, 32768)      : RoPE on Q (scale 0.125 -- EXACT in bf16; log2e-fold is
//                   permanently banned: 0.125*log2e is not bf16-representable
//                   and re-quantizes Q (round-5 failure, absmax 3.4e-3))
// [32768, 65536)  : RoPE on K (scale 1.0)
// [65536, 69632)  : V transpose vb [b][s][hd*64+n] -> vT [b][hd][n][s]
__global__ __launch_bounds__(256) void postproc(
    unsigned short* __restrict__ qb, unsigned short* __restrict__ kbuf,
    const unsigned short* __restrict__ vb, unsigned short* __restrict__ vT,
    const float* __restrict__ cos1, const float* __restrict__ sin1,
    const float* __restrict__ cos2, const float* __restrict__ sin2) {
  __shared__ unsigned short T[64][72];
  const int bid = blockIdx.x;
  if (bid < 65536) {
    unsigned short* q = (bid < 32768) ? qb : kbuf;
    const float scale = (bid < 32768) ? 0.125f : 1.0f;
    int tid = (bid & 32767) * 256 + threadIdx.x;
    int u = tid & 511;
    int m = tid >> 9;
    int s = m & (S_ - 1);
    int head = u >> 5, w = u & 31;
    size_t base = (size_t)m * D_ + head * 64;
    size_t c0, c1;
    float cv, sv;
    if (w < 8) {
      c0 = base + 2 * w; c1 = c0 + 1;
      cv = cos1[s * 8 + w]; sv = sin1[s * 8 + w];
    } else if (w < 20) {
      int j = w - 8, x = s & 31;
      c0 = base + 16 + j; c1 = base + 28 + j;
      cv = cos2[x * 12 + j]; sv = sin2[x * 12 + j];
    } else {
      int j = w - 20, yy = s >> 5;
      c0 = base + 40 + j; c1 = base + 52 + j;
      cv = cos2[yy * 12 + j]; sv = sin2[yy * 12 + j];
    }
    float a = bf2f(q[c0]), b = bf2f(q[c1]);
    q[c0] = f2bf((a * cv - b * sv) * scale);
    q[c1] = f2bf((a * sv + b * cv) * scale);
  } else {
    const int tb = bid - 65536;            // < 4096 = 16 st * 16 hd * 16 b
    const int t = threadIdx.x;
    const int st0 = (tb & 15) * 64;
    const int hd = (tb >> 4) & 15, b = tb >> 8;
    const unsigned short* src = vb + ((size_t)b * S_ + st0) * D_ + hd * 64;
#pragma unroll
    for (int rep = 0; rep < 4; ++rep) {
      int id = t + rep * 256;
      int s = id >> 4, n4 = (id & 15) * 4;
      short4v val = *(const short4v*)(src + (size_t)s * D_ + n4);
      T[n4 + 0][s] = val[0]; T[n4 + 1][s] = val[1];
      T[n4 + 2][s] = val[2]; T[n4 + 3][s] = val[3];
    }
    __syncthreads();
    unsigned short* dst = vT + ((size_t)(b * NH_ + hd) * 64) * S_ + st0;
#pragma unroll
    for (int rep = 0; rep < 2; ++rep) {
      int id = t + rep * 256;
      int n = id >> 3, s8 = (id & 7) * 8;
      unsigned short tmp[8];
#pragma unroll
      for (int u2 = 0; u2 < 8; ++u2) tmp[u2] = T[n][s8 + u2];
      *(short8v*)(dst + (size_t)n * S_ + s8) = *(short8v*)tmp;
    }
  }
}

// ---------------------------------------------------------------- MFMA flash attention
// grid = 2048 linear, swizzled: xcd=id%8, slot=id/8, qt=slot%8,
// pair=(slot/8)*8+xcd.  8 qt-blocks of a pair sit on ONE XCD -> K/V L2-resident.
// Block-shared double-buffered LDS K/V staging (round-4 2x win), swapped QK^T
// with in-register softmax, bpermute P-redistribution.  Unchanged from the
// passing round-4/6 kernel.
__global__ __launch_bounds__(256, 4) void attn_mfma(
    const unsigned short* __restrict__ qb, const unsigned short* __restrict__ kb,
    const unsigned short* __restrict__ vT, unsigned short* __restrict__ out) {
  __shared__ unsigned short KV[2][2][4096];   // [dbuf][K/V][64 rows x 64 elems]
  const int t = threadIdx.x;
  const int w = t >> 6;
  const int L = t & 63;
  const int c = L & 15;
  const int g = L >> 4;
  const int id = blockIdx.x;
  const int xcd = id & 7, slot = id >> 3;
  const int qt = slot & 7;
  const int pair = (slot >> 3) * 8 + xcd;
  const int b = pair >> 4, hd = pair & 15;
  const size_t mrow0 = (size_t)b * S_ + qt * 128 + w * 32;
  const int dcol0 = hd * 64;

  // staging lane geometry: lane L writes LDS bytes [seg*1024 + L*16, +16);
  // holds tile row seg*8+(L>>3), col-chunk (L&7); inverse-swizzle the SOURCE
  // col-chunk so reads can XOR with ((row&7)<<4)  (rule #21).
  const int lrow = L >> 3;
  const int lcol = ((L & 7) ^ lrow) * 8;

  // bpermute pull addresses (byte = 4*src_lane)
  const int a_lo = (((L & 16) ? 32 : 0) + c) * 4;
  const int a_hi = a_lo + 64;
  const bool ghi = (L >= 32);
  const int swz = (c & 7) << 3;                   // read-side XOR (elems)

  short8v aq[2][2];
#pragma unroll
  for (int i = 0; i < 2; ++i)
#pragma unroll
    for (int st = 0; st < 2; ++st)
      aq[i][st] = *(const short8v*)(qb + (mrow0 + 16 * i + c) * D_ + dcol0 + 32 * st + 8 * g);

  float4v oacc[2][4];
  float lsum[2] = {0.f, 0.f};
#pragma unroll
  for (int i = 0; i < 2; ++i)
#pragma unroll
    for (int jv = 0; jv < 4; ++jv) oacc[i][jv] = (float4v){0.f, 0.f, 0.f, 0.f};

  const unsigned short* vbase = vT + (size_t)(b * NH_ + hd) * 64 * S_;
  const unsigned short* kbb = kb + (size_t)b * S_ * D_ + dcol0;

#define STAGE(buf, kt_)                                                          \
  {                                                                              \
    _Pragma("unroll")                                                            \
    for (int e = 0; e < 2; ++e) {                                                \
      const int seg = 2 * w + e;                                                 \
      const int row = seg * 8 + lrow;                                            \
      load_lds16(kbb + (size_t)((kt_) * 64 + row) * D_ + lcol,                   \
                 &KV[buf][0][seg * 512]);                                        \
      load_lds16(vbase + (size_t)row * S_ + (kt_) * 64 + lcol,                   \
                 &KV[buf][1][seg * 512]);                                        \
    }                                                                            \
  }

  STAGE(0, 0);
  asm volatile("s_waitcnt vmcnt(0)" ::: "memory");
  __syncthreads();

#pragma unroll 1
  for (int kt = 0; kt < 16; ++kt) {
    const int cur = kt & 1;
    if (kt < 15) STAGE(cur ^ 1, kt + 1);
#pragma unroll
    for (int st = 0; st < 2; ++st) {
      short8v vfh[4];
#pragma unroll
      for (int jv = 0; jv < 4; ++jv)
        vfh[jv] = *(const short8v*)&KV[cur][1][((16 * jv + c) * 64 + st * 32 + 8 * g) ^ swz];
      short8v kfh[2][2];
#pragma unroll
      for (int jl = 0; jl < 2; ++jl)
#pragma unroll
        for (int h = 0; h < 2; ++h)
          kfh[jl][h] = *(const short8v*)&KV[cur][0][((16 * (2 * st + jl) + c) * 64 + h * 32 + 8 * g) ^ swz];
      float4v sacch[2][2];
#pragma unroll
      for (int i = 0; i < 2; ++i)
#pragma unroll
        for (int jl = 0; jl < 2; ++jl) sacch[i][jl] = (float4v){0.f, 0.f, 0.f, 0.f};
      __builtin_amdgcn_s_setprio(1);
#pragma unroll
      for (int jl = 0; jl < 2; ++jl)
#pragma unroll
        for (int i = 0; i < 2; ++i) {
          sacch[i][jl] = __builtin_amdgcn_mfma_f32_16x16x32_bf16(kfh[jl][0], aq[i][0], sacch[i][jl], 0, 0, 0);
          sacch[i][jl] = __builtin_amdgcn_mfma_f32_16x16x32_bf16(kfh[jl][1], aq[i][1], sacch[i][jl], 0, 0, 0);
        }
      __builtin_amdgcn_s_setprio(0);
      // in-register softmax: exp + lane-local row-sum + pack pairs to bf16 (RNE)
      unsigned pkh[2][2][2];
#pragma unroll
      for (int i = 0; i < 2; ++i)
#pragma unroll
        for (int jl = 0; jl < 2; ++jl) {
          float p0 = __expf(sacch[i][jl][0]);
          float p1 = __expf(sacch[i][jl][1]);
          float p2 = __expf(sacch[i][jl][2]);
          float p3 = __expf(sacch[i][jl][3]);
          lsum[i] += (p0 + p1) + (p2 + p3);
          pkh[i][jl][0] = pack2bf(p0, p1);
          pkh[i][jl][1] = pack2bf(p2, p3);
        }
      short8v aph[2];
#pragma unroll
      for (int i = 0; i < 2; ++i) {
        uint4v wv;
#pragma unroll
        for (int q2 = 0; q2 < 4; ++q2) {
          const int addr = (q2 & 2) ? a_hi : a_lo;
          int vlo = __builtin_amdgcn_ds_bpermute(addr, (int)pkh[i][0][q2 & 1]);
          int vhi = __builtin_amdgcn_ds_bpermute(addr, (int)pkh[i][1][q2 & 1]);
          wv[q2] = (unsigned)(ghi ? vhi : vlo);
        }
        aph[i] = *(short8v*)&wv;
      }
      __builtin_amdgcn_s_setprio(1);
#pragma unroll
      for (int jv = 0; jv < 4; ++jv)
#pragma unroll
        for (int i = 0; i < 2; ++i)
          oacc[i][jv] = __builtin_amdgcn_mfma_f32_16x16x32_bf16(aph[i], vfh[jv], oacc[i][jv], 0, 0, 0);
      __builtin_amdgcn_s_setprio(0);
    }
    asm volatile("s_waitcnt vmcnt(0)" ::: "memory");
    __syncthreads();
  }
#undef STAGE
#pragma unroll
  for (int i = 0; i < 2; ++i) {
    float ls = lsum[i];
    ls += __shfl_xor(ls, 16);
    ls += __shfl_xor(ls, 32);
#pragma unroll
    for (int r = 0; r < 4; ++r) {
      float inv = 1.f / __shfl(ls, 4 * g + r);
      size_t row = mrow0 + 16 * i + 4 * g + r;
#pragma unroll
      for (int jv = 0; jv < 4; ++jv)
        out[row * D_ + dcol0 + 16 * jv + c] = f2bf(oacc[i][jv][r] * inv);
    }
  }
}

// ---------------------------------------------------------------- launch
// Workspace (peak 168.03 MB < 192 MB proven):
//   [0,32)MB xb (reused as ob after QKV gemms) | [32,64) qb | [64,96) kb
//   [96,128) vb | [128,160) vT | [160,168) wqb..wob | [168,+32KB) tables
extern "C" void kernel_launch(void* const* d_in, const int* in_sizes, int n_in,
                              void* d_out, int out_size, void* d_ws, size_t ws_size,
                              hipStream_t stream) {
  const float* x  = (const float*)d_in[0];
  const float* Wq = (const float*)d_in[1];
  const float* bq = (const float*)d_in[2];
  const float* Wk = (const float*)d_in[3];
  const float* bk = (const float*)d_in[4];
  const float* Wv = (const float*)d_in[5];
  const float* bv = (const float*)d_in[6];
  const float* Wo = (const float*)d_in[7];
  const float* bo = (const float*)d_in[8];
  float* out = (float*)d_out;

  char* ws = (char*)d_ws;
  const size_t SZ2 = (size_t)M_TOT * D_ * 2;   // 32 MB
  unsigned short* xb = (unsigned short*)(ws);
  unsigned short* ob = xb;                               // alias: free after QKV gemms
  unsigned short* qb = (unsigned short*)(ws + SZ2);
  unsigned short* kb = (unsigned short*)(ws + 2 * SZ2);
  unsigned short* vb = (unsigned short*)(ws + 3 * SZ2);
  unsigned short* vT = (unsigned short*)(ws + 4 * SZ2);
  unsigned short* wqb = (unsigned short*)(ws + 5 * SZ2);
  unsigned short* wob = wqb + 3 * (size_t)D_ * D_;
  float* cos1 = (float*)(ws + 5 * SZ2 + 4 * (size_t)D_ * D_ * 2);
  float* sin1 = cos1 + S_ * 8;
  float* cos2 = sin1 + S_ * 8;
  float* sin2 = cos2 + 384;

  // 1) tables + x->bf16 + 4 weights->bf16
  prep<<<20514, 256, 0, stream>>>(x, xb, Wq, Wk, Wv, Wo, wqb,
                                  cos1, sin1, cos2, sin2);
  // 2) Q,K,V projections in one launch (grid.y selects W/bias/output)
  gemm_mfma<true><<<dim3(1024, 3), 256, 0, stream>>>(xb, wqb, bq, bk, bv, qb);
  // 3) ropeQ + ropeK + V-transpose in one launch
  postproc<<<69632, 256, 0, stream>>>(qb, kb, vb, vT, cos1, sin1, cos2, sin2);
  // 4) attention
  attn_mfma<<<2048, 256, 0, stream>>>(qb, kb, vT, ob);
  // 5) output projection (f32 out)
  gemm_mfma<false><<<dim3(1024, 1), 256, 0, stream>>>(ob, wob, bo, bo, bo, out);
}